// Round 7
// baseline (2868.777 us; speedup 1.0000x reference)
//
#include <hip/hip_runtime.h>

// Scatter-mean graph propagation, 8 rounds (4 fwd + 4 rev).
//
// 2D-TILED FAST PATH: round-5 profile showed e_pass is L1-transaction-bound
// (64M address-divergent 4B gathers of x[src] per pass; ~104us of TA
// transactions alone). Fix: second partition level so the gather is an LDS
// read.
//   Phase A: partition edges by db=dst>>12 (245 buckets), entry
//            (src<<12)|dstloc  (20+12=32 bits). Staged LDS scatter (round-5
//            proven pattern) -> coalesced writes.
//   c_pass : per-node in-degree counts from packed1 (once per direction).
//   Phase B: block per db: re-sort segment by sb=src>>13 (123 tiles) into
//            packed2, entry (srcloc<<12)|dstloc (13+12=25 bits), plus cell
//            offsets. Reads are L3-resident (128MB just written).
//   t_pass : block per db: for each src-tile {stage 32KB x-tile to LDS;
//            edges: acc[dstloc] += xt[srcloc] - both LDS}. packed2 read
//            sequentially with nontemporal loads (keep L2 for x slices).
//            Fused normalize with cached counts.
//
// MID PATH (ws too small for packed2): phase A + c_pass + gather-style e_pass
// (round-5 behavior).
// FALLBACK: global-atomic version (insurance for weird shapes).
//
// s1_totals writes its result into the first NDB words of 'start' (scratch
// reuse); s3_start later overwrites 'start' and depends only on blkcnt+base.

typedef unsigned uint32x4 __attribute__((ext_vector_type(4)));

#define TPB_E 1024
#define NPART 512
#define TPB_P 512
#define BATCHA 8192
#define CAPA 64
#define NDBMAX 256     // max dst buckets (N <= 2^20)
#define DSH 12         // dst bucket shift (4096 nodes)
#define DMASK 4095u
#define SSH 13         // src tile shift (8192 nodes)
#define SMASK 8191u
#define NSBMAX 128
#define BATCHB 4096
#define CAPB 64

// ---------------- phase A: partition by dst bucket ----------------

__global__ __launch_bounds__(TPB_P)
void p1_count(const int* __restrict__ dst, unsigned* __restrict__ blkcnt,
              int E, int chunk, int NB) {
    __shared__ unsigned h[NDBMAX];
    for (int i = threadIdx.x; i < NB; i += TPB_P) h[i] = 0u;
    __syncthreads();
    int beg = blockIdx.x * chunk;
    int end = min(beg + chunk, E);
    int len = end - beg; if (len < 0) len = 0;
    const uint32x4* d4 = (const uint32x4*)(dst + beg);   // beg multiple of 16
    int n4 = len >> 2;
    for (int i = threadIdx.x; i < n4; i += TPB_P) {
        uint32x4 d = __builtin_nontemporal_load(&d4[i]);
        atomicAdd(&h[d.x >> DSH], 1u);
        atomicAdd(&h[d.y >> DSH], 1u);
        atomicAdd(&h[d.z >> DSH], 1u);
        atomicAdd(&h[d.w >> DSH], 1u);
    }
    __syncthreads();
    unsigned* o = blkcnt + (size_t)blockIdx.x * NB;
    for (int i = threadIdx.x; i < NB; i += TPB_P) o[i] = h[i];
}

__global__ __launch_bounds__(TPB_P)
void s1_totals(const unsigned* __restrict__ blkcnt, unsigned* __restrict__ totals,
               int NB, int nblk) {
    __shared__ unsigned red[TPB_P];
    int b = blockIdx.x;
    unsigned s = 0;
    for (int k = threadIdx.x; k < nblk; k += TPB_P) s += blkcnt[(size_t)k * NB + b];
    red[threadIdx.x] = s;
    __syncthreads();
    for (int off = TPB_P / 2; off > 0; off >>= 1) {
        if (threadIdx.x < off) red[threadIdx.x] += red[threadIdx.x + off];
        __syncthreads();
    }
    if (threadIdx.x == 0) totals[b] = red[0];
}

__global__ __launch_bounds__(TPB_P)
void s2_scan(const unsigned* __restrict__ totals, unsigned* __restrict__ base, int NB) {
    __shared__ unsigned t[TPB_P];
    int tid = threadIdx.x;
    unsigned v = (tid < NB) ? totals[tid] : 0u;
    t[tid] = v;
    __syncthreads();
    for (int off = 1; off < TPB_P; off <<= 1) {
        unsigned w = (tid >= off) ? t[tid - off] : 0u;
        __syncthreads();
        t[tid] += w;
        __syncthreads();
    }
    if (tid < NB) base[tid] = t[tid] - v;
    if (tid == NB - 1) base[NB] = t[tid];
}

__global__ __launch_bounds__(TPB_P)
void s3_start(const unsigned* __restrict__ blkcnt, const unsigned* __restrict__ base,
              unsigned* __restrict__ start, int NB, int nblk) {
    __shared__ unsigned t[TPB_P];
    int b = blockIdx.x;
    int tid = threadIdx.x;
    unsigned v = (tid < nblk) ? blkcnt[(size_t)tid * NB + b] : 0u;
    t[tid] = v;
    __syncthreads();
    for (int off = 1; off < TPB_P; off <<= 1) {
        unsigned w = (tid >= off) ? t[tid - off] : 0u;
        __syncthreads();
        t[tid] += w;
        __syncthreads();
    }
    if (tid < nblk) start[(size_t)tid * NB + b] = base[b] + t[tid] - v;
}

__global__ __launch_bounds__(TPB_P)
void p2_scatter(const int* __restrict__ src, const int* __restrict__ dst,
                const unsigned* __restrict__ start, unsigned* __restrict__ packed,
                int E, int chunk, int NB) {
    __shared__ unsigned stg[NDBMAX * CAPA];   // 64 KB staging
    __shared__ unsigned h[NDBMAX];
    __shared__ unsigned gcur[NDBMAX];
    int tid = threadIdx.x;
    int bid = blockIdx.x;
    for (int i = tid; i < NB; i += TPB_P) gcur[i] = start[(size_t)bid * NB + i];
    int beg = bid * chunk;
    int end = min(beg + chunk, E);
    int wid = tid >> 6, lane = tid & 63;
    for (int bb = beg; bb < end; bb += BATCHA) {
        int bend = min(bb + BATCHA, end);
        int n4 = (bend - bb) >> 2;          // batch multiple of 16
        for (int i = tid; i < NB; i += TPB_P) h[i] = 0u;
        __syncthreads();
        const uint32x4* s4 = (const uint32x4*)(src + bb);
        const uint32x4* d4 = (const uint32x4*)(dst + bb);
        for (int i = tid; i < n4; i += TPB_P) {
            uint32x4 s = __builtin_nontemporal_load(&s4[i]);
            uint32x4 d = __builtin_nontemporal_load(&d4[i]);
            unsigned sv[4] = {s.x, s.y, s.z, s.w};
            unsigned dv[4] = {d.x, d.y, d.z, d.w};
            #pragma unroll
            for (int k = 0; k < 4; ++k) {
                unsigned b = dv[k] >> DSH;
                unsigned val = (sv[k] << DSH) | (dv[k] & DMASK);
                unsigned pos = atomicAdd(&h[b], 1u);
                if (pos < CAPA) stg[(b << 6) + ((pos + b) & 63u)] = val;  // bank-rotated
                else packed[gcur[b] + pos] = val;   // rare overflow
            }
        }
        __syncthreads();
        for (int b = wid; b < NB; b += TPB_P / 64) {
            unsigned cnt = h[b];
            unsigned n = cnt < CAPA ? cnt : CAPA;
            unsigned g0 = gcur[b];
            for (unsigned i = lane; i < n; i += 64)
                packed[g0 + i] = stg[(b << 6) + ((i + b) & 63u)];
            if (lane == 0) gcur[b] = g0 + cnt;
        }
        __syncthreads();
    }
}

// ---------------- counts (once per direction) ----------------

__global__ __launch_bounds__(TPB_E)
void c_pass(const unsigned* __restrict__ packed1, const unsigned* __restrict__ base,
            float* __restrict__ cnt, int N) {
    __shared__ unsigned c[1 << DSH];   // 16 KB
    int db = blockIdx.x, tid = threadIdx.x;
    for (int i = tid; i < (1 << DSH); i += TPB_E) c[i] = 0u;
    __syncthreads();
    int beg = (int)base[db], end = (int)base[db + 1];
    for (int e = beg + tid; e < end; e += TPB_E)
        atomicAdd(&c[packed1[e] & DMASK], 1u);
    __syncthreads();
    int nbase = db << DSH;
    int nmax = min(N - nbase, 1 << DSH);
    for (int i = tid; i < nmax; i += TPB_E) cnt[nbase + i] = (float)c[i];
}

// ---------------- phase B: per-db re-sort by src tile ----------------

__global__ __launch_bounds__(TPB_E)
void b_repart(const unsigned* __restrict__ packed1, const unsigned* __restrict__ base,
              unsigned* __restrict__ packed2, unsigned* __restrict__ celloff,
              int NSB) {
    __shared__ unsigned h[NSBMAX];
    __shared__ unsigned gcur[NSBMAX];
    __shared__ unsigned stg[NSBMAX * CAPB];   // 32 KB
    int db = blockIdx.x;
    int tid = threadIdx.x;
    int segbeg = (int)base[db], segend = (int)base[db + 1];
    // pass 1: histogram by src tile
    for (int i = tid; i < NSB; i += TPB_E) h[i] = 0u;
    __syncthreads();
    for (int e = segbeg + tid; e < segend; e += TPB_E)
        atomicAdd(&h[packed1[e] >> (DSH + SSH)], 1u);
    __syncthreads();
    if (tid == 0) {   // tiny serial scan (<=128 elements)
        unsigned run = (unsigned)segbeg;
        for (int i = 0; i < NSB; ++i) {
            unsigned c = h[i];
            gcur[i] = run;
            celloff[(size_t)db * (NSB + 1) + i] = run;
            run += c;
        }
        celloff[(size_t)db * (NSB + 1) + NSB] = run;   // == segend
    }
    __syncthreads();
    int wid = tid >> 6, lane = tid & 63;
    for (int bb = segbeg; bb < segend; bb += BATCHB) {
        int bend = min(bb + BATCHB, segend);
        for (int i = tid; i < NSB; i += TPB_E) h[i] = 0u;
        __syncthreads();
        for (int e = bb + tid; e < bend; e += TPB_E) {
            unsigned p = packed1[e];
            unsigned sb = p >> (DSH + SSH);
            unsigned v = (((p >> DSH) & SMASK) << DSH) | (p & DMASK);
            unsigned pos = atomicAdd(&h[sb], 1u);
            if (pos < CAPB) stg[(sb << 6) + ((pos + sb) & 63u)] = v;
            else packed2[gcur[sb] + pos] = v;
        }
        __syncthreads();
        for (int b = wid; b < NSB; b += TPB_E / 64) {
            unsigned cnt = h[b];
            unsigned n = cnt < CAPB ? cnt : CAPB;
            unsigned g0 = gcur[b];
            for (unsigned i = lane; i < n; i += 64)
                packed2[g0 + i] = stg[(b << 6) + ((i + b) & 63u)];
            if (lane == 0) gcur[b] = g0 + cnt;
        }
        __syncthreads();
    }
}

// ---------------- t_pass: LDS-gather edge pass ----------------

__global__ __launch_bounds__(TPB_E)
void t_pass(const float* __restrict__ x, const unsigned* __restrict__ packed2,
            const unsigned* __restrict__ celloff, const float* __restrict__ cnt,
            float* __restrict__ outslice, int N, int NSB) {
    __shared__ float xt[1 << SSH];    // 32 KB src tile
    __shared__ float acc[1 << DSH];   // 16 KB dst accumulator
    int tid = threadIdx.x;
    int db = blockIdx.x;
    for (int i = tid; i < (1 << DSH); i += TPB_E) acc[i] = 0.0f;
    const unsigned* co = celloff + (size_t)db * (NSB + 1);
    for (int sb = 0; sb < NSB; ++sb) {
        __syncthreads();   // protect xt from previous iteration's readers (also covers acc init)
        int tbase = sb << SSH;
        int navail = min(N - tbase, 1 << SSH);
        int n4 = navail >> 2;
        const float4* x4 = (const float4*)(x + tbase);
        for (int i = tid; i < n4; i += TPB_E) ((float4*)xt)[i] = x4[i];
        for (int i = (n4 << 2) + tid; i < navail; i += TPB_E) xt[i] = x[tbase + i];
        for (int i = navail + tid; i < (1 << SSH); i += TPB_E) xt[i] = 0.0f;
        __syncthreads();
        int beg = (int)co[sb], end = (int)co[sb + 1];
        for (int e = beg + tid; e < end; e += TPB_E) {
            unsigned p = __builtin_nontemporal_load(&packed2[e]);
            atomicAdd(&acc[p & DMASK], xt[p >> DSH]);
        }
    }
    __syncthreads();
    int nbase = db << DSH;
    int nmax = min(N - nbase, 1 << DSH);
    for (int i = tid; i < nmax; i += TPB_E)
        outslice[nbase + i] = acc[i] / fmaxf(cnt[nbase + i], 1.0f);
}

// ---------------- mid path: gather-style edge pass (round-5 proven) ----------------

__global__ __launch_bounds__(TPB_E)
void e_pass12(const float* __restrict__ x, const unsigned* __restrict__ packed,
              const unsigned* __restrict__ boff, const float* __restrict__ cnt,
              float* __restrict__ outslice, int N) {
    __shared__ float acc[1 << DSH];
    int tid = threadIdx.x;
    for (int i = tid; i < (1 << DSH); i += TPB_E) acc[i] = 0.0f;
    __syncthreads();
    int b = blockIdx.x;
    int beg = (int)boff[b], end = (int)boff[b + 1];
    int a0 = min((beg + 3) & ~3, end);
    for (int e = beg + tid; e < a0; e += TPB_E) {
        unsigned p = packed[e];
        atomicAdd(&acc[p & DMASK], x[p >> DSH]);
    }
    int i0 = a0 >> 2, i1 = i0 + ((end - a0) >> 2);
    const uint32x4* p4 = (const uint32x4*)packed;
    for (int i = i0 + tid; i < i1; i += TPB_E) {
        uint32x4 p = p4[i];
        atomicAdd(&acc[p.x & DMASK], x[p.x >> DSH]);
        atomicAdd(&acc[p.y & DMASK], x[p.y >> DSH]);
        atomicAdd(&acc[p.z & DMASK], x[p.z >> DSH]);
        atomicAdd(&acc[p.w & DMASK], x[p.w >> DSH]);
    }
    for (int e = a0 + ((end - a0) & ~3) + tid; e < end; e += TPB_E) {
        unsigned p = packed[e];
        atomicAdd(&acc[p & DMASK], x[p >> DSH]);
    }
    __syncthreads();
    int nbase = b << DSH;
    int nmax = min(N - nbase, 1 << DSH);
    for (int i = tid; i < nmax; i += TPB_E)
        outslice[nbase + i] = acc[i] / fmaxf(cnt[nbase + i], 1.0f);
}

// ---------------- fallback (global atomics) ----------------

#define TPB 256
#define MAX_BLOCKS 2048

__global__ void round_first(const float* __restrict__ x, const int* __restrict__ src,
                            const int* __restrict__ dst, float* __restrict__ agg,
                            float* __restrict__ cnt, int nE) {
    int i = blockIdx.x * blockDim.x + threadIdx.x;
    int stride = gridDim.x * blockDim.x;
    for (; i < nE; i += stride) {
        atomicAdd(&agg[dst[i]], x[src[i]]);
        atomicAdd(&cnt[dst[i]], 1.0f);
    }
}

__global__ void round_next(const float* __restrict__ x, const int* __restrict__ src,
                           const int* __restrict__ dst, float* __restrict__ agg, int nE) {
    int i = blockIdx.x * blockDim.x + threadIdx.x;
    int stride = gridDim.x * blockDim.x;
    for (; i < nE; i += stride) atomicAdd(&agg[dst[i]], x[src[i]]);
}

__global__ void normalize_k(float* __restrict__ out, const float* __restrict__ cnt, int n) {
    int i = blockIdx.x * blockDim.x + threadIdx.x;
    int stride = gridDim.x * blockDim.x;
    for (; i < n; i += stride) out[i] /= fmaxf(cnt[i], 1.0f);
}

// ---------------- launch ----------------

extern "C" void kernel_launch(void* const* d_in, const int* in_sizes, int n_in,
                              void* d_out, int out_size, void* d_ws, size_t ws_size,
                              hipStream_t stream) {
    const float* topic = (const float*)d_in[0];
    const int* ei  = (const int*)d_in[1];
    const int* rei = (const int*)d_in[2];
    const int N = in_sizes[0];
    const int E = in_sizes[1] / 2;

    float* out = (float*)d_out;   // 8 slices of N floats

    const int NDB = (N + (int)DMASK) >> DSH;
    const int NSB = (N + (int)SMASK) >> SSH;
    const int chunk = ((E + NPART * 16 - 1) / (NPART * 16)) * 16;

    size_t off = 0;
    auto alloc = [&](size_t bytes) { size_t o = off; off += (bytes + 255) & ~(size_t)255; return o; };
    size_t o_packed1 = alloc((size_t)E * 4);
    size_t o_cnt     = alloc((size_t)N * 4);
    size_t o_blkcnt  = alloc((size_t)NPART * NDB * 4);
    size_t o_start   = alloc((size_t)NPART * NDB * 4);
    size_t o_base    = alloc((size_t)(NDBMAX + 1) * 4);
    size_t need_mid  = off;
    size_t o_packed2 = alloc((size_t)E * 4);
    size_t o_celloff = alloc((size_t)NDB * (NSB + 1) * 4);
    size_t need_2d   = off;

    bool shapes_ok = (NDB >= 2) && (NDB <= NDBMAX) && (NSB >= 1) && (NSB <= NSBMAX) &&
                     (N <= (1 << 20)) && (E % 16 == 0) && (E > 0);
    bool full = shapes_ok && (need_2d <= ws_size);
    bool mid  = shapes_ok && (need_mid <= ws_size);

    if (full || mid) {
        char* ws = (char*)d_ws;
        unsigned* packed1 = (unsigned*)(ws + o_packed1);
        float*    cnt     = (float*)   (ws + o_cnt);
        unsigned* blkcnt  = (unsigned*)(ws + o_blkcnt);
        unsigned* start   = (unsigned*)(ws + o_start);
        unsigned* base    = (unsigned*)(ws + o_base);
        unsigned* packed2 = full ? (unsigned*)(ws + o_packed2) : nullptr;
        unsigned* celloff = full ? (unsigned*)(ws + o_celloff) : nullptr;

        for (int dir = 0; dir < 2; ++dir) {
            const int* src = (dir == 0) ? ei : rei;
            const int* dst = src + E;
            float* oslab = out + (size_t)dir * 4 * N;

            // phase A: partition by dst bucket.
            // 'start' first NDB words double as totals scratch (overwritten by s3_start).
            p1_count<<<NPART, TPB_P, 0, stream>>>(dst, blkcnt, E, chunk, NDB);
            s1_totals<<<NDB, TPB_P, 0, stream>>>(blkcnt, start, NDB, NPART);
            s2_scan<<<1, TPB_P, 0, stream>>>(start, base, NDB);
            s3_start<<<NDB, TPB_P, 0, stream>>>(blkcnt, base, start, NDB, NPART);
            p2_scatter<<<NPART, TPB_P, 0, stream>>>(src, dst, start, packed1, E, chunk, NDB);

            c_pass<<<NDB, TPB_E, 0, stream>>>(packed1, base, cnt, N);

            if (full) {
                b_repart<<<NDB, TPB_E, 0, stream>>>(packed1, base, packed2, celloff, NSB);
                t_pass<<<NDB, TPB_E, 0, stream>>>(topic, packed2, celloff, cnt, oslab, N, NSB);
                for (int r = 1; r < 4; ++r)
                    t_pass<<<NDB, TPB_E, 0, stream>>>(oslab + (size_t)(r - 1) * N, packed2,
                                                      celloff, cnt, oslab + (size_t)r * N, N, NSB);
            } else {
                e_pass12<<<NDB, TPB_E, 0, stream>>>(topic, packed1, base, cnt, oslab, N);
                for (int r = 1; r < 4; ++r)
                    e_pass12<<<NDB, TPB_E, 0, stream>>>(oslab + (size_t)(r - 1) * N, packed1,
                                                        base, cnt, oslab + (size_t)r * N, N);
            }
        }
        return;
    }

    // -------- fallback: global-atomic version --------
    const int* src = ei;
    const int* dst = ei + E;
    const int* rsrc = rei;
    const int* rdst = rei + E;

    float* cnt_f = (float*)d_ws;
    float* cnt_r = cnt_f + N;

    (void)hipMemsetAsync(d_out, 0, (size_t)out_size * sizeof(float), stream);
    (void)hipMemsetAsync(d_ws, 0, (size_t)2 * N * sizeof(float), stream);

    int eb = (E + TPB - 1) / TPB; if (eb > MAX_BLOCKS) eb = MAX_BLOCKS;
    int nb = (N + TPB - 1) / TPB; if (nb > MAX_BLOCKS) nb = MAX_BLOCKS;

    round_first<<<eb, TPB, 0, stream>>>(topic, src, dst, out, cnt_f, E);
    normalize_k<<<nb, TPB, 0, stream>>>(out, cnt_f, N);
    for (int r = 1; r < 4; ++r) {
        round_next<<<eb, TPB, 0, stream>>>(out + (size_t)(r - 1) * N, src, dst,
                                           out + (size_t)r * N, E);
        normalize_k<<<nb, TPB, 0, stream>>>(out + (size_t)r * N, cnt_f, N);
    }
    round_first<<<eb, TPB, 0, stream>>>(topic, rsrc, rdst, out + (size_t)4 * N, cnt_r, E);
    normalize_k<<<nb, TPB, 0, stream>>>(out + (size_t)4 * N, cnt_r, N);
    for (int r = 5; r < 8; ++r) {
        round_next<<<eb, TPB, 0, stream>>>(out + (size_t)(r - 1) * N, rsrc, rdst,
                                           out + (size_t)r * N, E);
        normalize_k<<<nb, TPB, 0, stream>>>(out + (size_t)r * N, cnt_r, N);
    }
}

// Round 8
// 2336.306 us; speedup vs baseline: 1.2279x; 1.2279x over previous
//
#include <hip/hip_runtime.h>

// Scatter-mean graph propagation, 8 rounds (4 fwd + 4 rev).
//
// Round-7 post-mortem: one-db-per-block t_pass was latency-bound (123 tiny
// barrier phases, ~2 edges/thread/phase) and restaged x 245x (963MB L3/pass).
// Round-8 design:
//   Phase A (unchanged, proven): partition by db=dst>>12 (245 buckets),
//     packed1=(src<<12)|dstloc, staged-LDS scatter for coalesced writes.
//   c_pass (unchanged): per-node counts.
//   b_repart (unchanged): per-db sort by src-tile sb=src>>13 (123 tiles),
//     packed2=(srcloc13<<12)|dstloc12, celloff[db][sb].
//   t_pass2 (new): block=(superbucket s of 4 dbs, src-chunk c of NC=4).
//     acc[4*4096]=64KB covers 4 dbs; xt double-buffered 2x32KB (LDS 128KB).
//     Per tile: issue next-tile loads to regs (T14), process 4 runs
//     (4 waves each, ~4 edges/thread), write regs->xt[next], ONE barrier.
//     Restage drops to 62 x 4MB = 248MB/pass; phases 4.3K edges each.
//     Partials (62x4x64KB=16MB) land in the dead packed1 region; combine_k
//     sums NC partials and divides by cnt.
//
// MID PATH (ws too small): phase A + c_pass + gather e_pass (round-5, 188us).
// FALLBACK: global-atomic version.

typedef unsigned uint32x4 __attribute__((ext_vector_type(4)));

#define TPB_E 1024
#define NPART 512
#define TPB_P 512
#define BATCHA 8192
#define CAPA 64
#define NDBMAX 256     // max dst buckets (N <= 2^20)
#define DSH 12         // dst bucket shift (4096 nodes)
#define DMASK 4095u
#define SSH 13         // src tile shift (8192 nodes)
#define SMASK 8191u
#define NSBMAX 128
#define BATCHB 4096
#define CAPB 64
#define SUPER 4        // dbs per superbucket in t_pass2
#define NC 4           // src-range chunks in t_pass2

// ---------------- phase A: partition by dst bucket ----------------

__global__ __launch_bounds__(TPB_P)
void p1_count(const int* __restrict__ dst, unsigned* __restrict__ blkcnt,
              int E, int chunk, int NB) {
    __shared__ unsigned h[NDBMAX];
    for (int i = threadIdx.x; i < NB; i += TPB_P) h[i] = 0u;
    __syncthreads();
    int beg = blockIdx.x * chunk;
    int end = min(beg + chunk, E);
    int len = end - beg; if (len < 0) len = 0;
    const uint32x4* d4 = (const uint32x4*)(dst + beg);   // beg multiple of 16
    int n4 = len >> 2;
    for (int i = threadIdx.x; i < n4; i += TPB_P) {
        uint32x4 d = __builtin_nontemporal_load(&d4[i]);
        atomicAdd(&h[d.x >> DSH], 1u);
        atomicAdd(&h[d.y >> DSH], 1u);
        atomicAdd(&h[d.z >> DSH], 1u);
        atomicAdd(&h[d.w >> DSH], 1u);
    }
    __syncthreads();
    unsigned* o = blkcnt + (size_t)blockIdx.x * NB;
    for (int i = threadIdx.x; i < NB; i += TPB_P) o[i] = h[i];
}

__global__ __launch_bounds__(TPB_P)
void s1_totals(const unsigned* __restrict__ blkcnt, unsigned* __restrict__ totals,
               int NB, int nblk) {
    __shared__ unsigned red[TPB_P];
    int b = blockIdx.x;
    unsigned s = 0;
    for (int k = threadIdx.x; k < nblk; k += TPB_P) s += blkcnt[(size_t)k * NB + b];
    red[threadIdx.x] = s;
    __syncthreads();
    for (int off = TPB_P / 2; off > 0; off >>= 1) {
        if (threadIdx.x < off) red[threadIdx.x] += red[threadIdx.x + off];
        __syncthreads();
    }
    if (threadIdx.x == 0) totals[b] = red[0];
}

__global__ __launch_bounds__(TPB_P)
void s2_scan(const unsigned* __restrict__ totals, unsigned* __restrict__ base, int NB) {
    __shared__ unsigned t[TPB_P];
    int tid = threadIdx.x;
    unsigned v = (tid < NB) ? totals[tid] : 0u;
    t[tid] = v;
    __syncthreads();
    for (int off = 1; off < TPB_P; off <<= 1) {
        unsigned w = (tid >= off) ? t[tid - off] : 0u;
        __syncthreads();
        t[tid] += w;
        __syncthreads();
    }
    if (tid < NB) base[tid] = t[tid] - v;
    if (tid == NB - 1) base[NB] = t[tid];
}

__global__ __launch_bounds__(TPB_P)
void s3_start(const unsigned* __restrict__ blkcnt, const unsigned* __restrict__ base,
              unsigned* __restrict__ start, int NB, int nblk) {
    __shared__ unsigned t[TPB_P];
    int b = blockIdx.x;
    int tid = threadIdx.x;
    unsigned v = (tid < nblk) ? blkcnt[(size_t)tid * NB + b] : 0u;
    t[tid] = v;
    __syncthreads();
    for (int off = 1; off < TPB_P; off <<= 1) {
        unsigned w = (tid >= off) ? t[tid - off] : 0u;
        __syncthreads();
        t[tid] += w;
        __syncthreads();
    }
    if (tid < nblk) start[(size_t)tid * NB + b] = base[b] + t[tid] - v;
}

__global__ __launch_bounds__(TPB_P)
void p2_scatter(const int* __restrict__ src, const int* __restrict__ dst,
                const unsigned* __restrict__ start, unsigned* __restrict__ packed,
                int E, int chunk, int NB) {
    __shared__ unsigned stg[NDBMAX * CAPA];   // 64 KB staging
    __shared__ unsigned h[NDBMAX];
    __shared__ unsigned gcur[NDBMAX];
    int tid = threadIdx.x;
    int bid = blockIdx.x;
    for (int i = tid; i < NB; i += TPB_P) gcur[i] = start[(size_t)bid * NB + i];
    int beg = bid * chunk;
    int end = min(beg + chunk, E);
    int wid = tid >> 6, lane = tid & 63;
    for (int bb = beg; bb < end; bb += BATCHA) {
        int bend = min(bb + BATCHA, end);
        int n4 = (bend - bb) >> 2;          // batch multiple of 16
        for (int i = tid; i < NB; i += TPB_P) h[i] = 0u;
        __syncthreads();
        const uint32x4* s4 = (const uint32x4*)(src + bb);
        const uint32x4* d4 = (const uint32x4*)(dst + bb);
        for (int i = tid; i < n4; i += TPB_P) {
            uint32x4 s = __builtin_nontemporal_load(&s4[i]);
            uint32x4 d = __builtin_nontemporal_load(&d4[i]);
            unsigned sv[4] = {s.x, s.y, s.z, s.w};
            unsigned dv[4] = {d.x, d.y, d.z, d.w};
            #pragma unroll
            for (int k = 0; k < 4; ++k) {
                unsigned b = dv[k] >> DSH;
                unsigned val = (sv[k] << DSH) | (dv[k] & DMASK);
                unsigned pos = atomicAdd(&h[b], 1u);
                if (pos < CAPA) stg[(b << 6) + ((pos + b) & 63u)] = val;  // bank-rotated
                else packed[gcur[b] + pos] = val;   // rare overflow
            }
        }
        __syncthreads();
        for (int b = wid; b < NB; b += TPB_P / 64) {
            unsigned cnt = h[b];
            unsigned n = cnt < CAPA ? cnt : CAPA;
            unsigned g0 = gcur[b];
            for (unsigned i = lane; i < n; i += 64)
                packed[g0 + i] = stg[(b << 6) + ((i + b) & 63u)];
            if (lane == 0) gcur[b] = g0 + cnt;
        }
        __syncthreads();
    }
}

// ---------------- counts (once per direction) ----------------

__global__ __launch_bounds__(TPB_E)
void c_pass(const unsigned* __restrict__ packed1, const unsigned* __restrict__ base,
            float* __restrict__ cnt, int N) {
    __shared__ unsigned c[1 << DSH];   // 16 KB
    int db = blockIdx.x, tid = threadIdx.x;
    for (int i = tid; i < (1 << DSH); i += TPB_E) c[i] = 0u;
    __syncthreads();
    int beg = (int)base[db], end = (int)base[db + 1];
    for (int e = beg + tid; e < end; e += TPB_E)
        atomicAdd(&c[packed1[e] & DMASK], 1u);
    __syncthreads();
    int nbase = db << DSH;
    int nmax = min(N - nbase, 1 << DSH);
    for (int i = tid; i < nmax; i += TPB_E) cnt[nbase + i] = (float)c[i];
}

// ---------------- phase B: per-db re-sort by src tile ----------------

__global__ __launch_bounds__(TPB_E)
void b_repart(const unsigned* __restrict__ packed1, const unsigned* __restrict__ base,
              unsigned* __restrict__ packed2, unsigned* __restrict__ celloff,
              int NSB) {
    __shared__ unsigned h[NSBMAX];
    __shared__ unsigned gcur[NSBMAX];
    __shared__ unsigned stg[NSBMAX * CAPB];   // 32 KB
    int db = blockIdx.x;
    int tid = threadIdx.x;
    int segbeg = (int)base[db], segend = (int)base[db + 1];
    for (int i = tid; i < NSB; i += TPB_E) h[i] = 0u;
    __syncthreads();
    for (int e = segbeg + tid; e < segend; e += TPB_E)
        atomicAdd(&h[packed1[e] >> (DSH + SSH)], 1u);
    __syncthreads();
    if (tid == 0) {   // tiny serial scan (<=128 elements)
        unsigned run = (unsigned)segbeg;
        for (int i = 0; i < NSB; ++i) {
            unsigned c = h[i];
            gcur[i] = run;
            celloff[(size_t)db * (NSB + 1) + i] = run;
            run += c;
        }
        celloff[(size_t)db * (NSB + 1) + NSB] = run;   // == segend
    }
    __syncthreads();
    int wid = tid >> 6, lane = tid & 63;
    for (int bb = segbeg; bb < segend; bb += BATCHB) {
        int bend = min(bb + BATCHB, segend);
        for (int i = tid; i < NSB; i += TPB_E) h[i] = 0u;
        __syncthreads();
        for (int e = bb + tid; e < bend; e += TPB_E) {
            unsigned p = packed1[e];
            unsigned sb = p >> (DSH + SSH);
            unsigned v = (((p >> DSH) & SMASK) << DSH) | (p & DMASK);
            unsigned pos = atomicAdd(&h[sb], 1u);
            if (pos < CAPB) stg[(sb << 6) + ((pos + sb) & 63u)] = v;
            else packed2[gcur[sb] + pos] = v;
        }
        __syncthreads();
        for (int b = wid; b < NSB; b += TPB_E / 64) {
            unsigned cnt = h[b];
            unsigned n = cnt < CAPB ? cnt : CAPB;
            unsigned g0 = gcur[b];
            for (unsigned i = lane; i < n; i += 64)
                packed2[g0 + i] = stg[(b << 6) + ((i + b) & 63u)];
            if (lane == 0) gcur[b] = g0 + cnt;
        }
        __syncthreads();
    }
}

// ---------------- t_pass2: superbucket LDS edge pass ----------------
// block = (superbucket s: 4 dbs, chunk c: NC tile-chunks). acc 64KB, xt 2x32KB.

__global__ __launch_bounds__(TPB_E)
void t_pass2(const float* __restrict__ x, const unsigned* __restrict__ packed2,
             const unsigned* __restrict__ celloff, float* __restrict__ partial,
             int N, int NDB, int NSB) {
    __shared__ float acc[SUPER << DSH];   // 16384 floats = 64 KB
    __shared__ float xt[2][1 << SSH];     // 2 x 8192 floats = 64 KB
    const int tid = threadIdx.x;
    const int s = blockIdx.x;
    const int c = blockIdx.y;
    const int tiles_per = (NSB + NC - 1) / NC;
    const int sb0 = c * tiles_per;
    const int sb1 = min(sb0 + tiles_per, NSB);
    for (int i = tid; i < (SUPER << DSH); i += TPB_E) acc[i] = 0.0f;

    // prologue: stage tile sb0 into xt[0]
    if (sb0 < sb1) {
        int tb = sb0 << SSH;
        int avail = min(N - tb, 1 << SSH);
        if (avail == (1 << SSH)) {
            const float4* xs = (const float4*)(x + tb);
            ((float4*)xt[0])[tid] = xs[tid];
            ((float4*)xt[0])[tid + TPB_E] = xs[tid + TPB_E];
        } else {
            for (int i = tid; i < (1 << SSH); i += TPB_E)
                xt[0][i] = (i < avail) ? x[tb + i] : 0.0f;
        }
    }
    __syncthreads();

    const int wid = tid >> 6, lane = tid & 63;
    const int jr = wid & (SUPER - 1);                 // which db of the super
    const int gidx = ((wid / SUPER) << 6) + lane;     // 0..255 within run group
    const int gstr = (TPB_E / 64 / SUPER) * 64;       // 256
    int cur = 0;
    for (int sb = sb0; sb < sb1; ++sb) {
        // T14 async split: issue next-tile loads into regs BEFORE edge work
        float4 a0, a1;
        int havenext = 0, scalar_next = 0, ntb = 0;
        if (sb + 1 < sb1) {
            ntb = (sb + 1) << SSH;
            int avail = min(N - ntb, 1 << SSH);
            if (avail == (1 << SSH)) {
                const float4* xs = (const float4*)(x + ntb);
                a0 = xs[tid];
                a1 = xs[tid + TPB_E];
                havenext = 1;
            } else scalar_next = 1;   // boundary tile: stage after edge work
        }
        // edge work: 4 runs (one per db of super), 4 waves each
        int db = s * SUPER + jr;
        if (db < NDB) {
            const unsigned* co = celloff + (size_t)db * (NSB + 1);
            int beg = (int)co[sb], end = (int)co[sb + 1];
            unsigned jb = (unsigned)jr << DSH;
            const float* xb = xt[cur];
            for (int e = beg + gidx; e < end; e += gstr) {
                unsigned p = packed2[e];
                atomicAdd(&acc[jb + (p & DMASK)], xb[p >> DSH]);
            }
        }
        // write next tile into the other buffer (no reader conflict)
        if (havenext) {
            ((float4*)xt[cur ^ 1])[tid] = a0;
            ((float4*)xt[cur ^ 1])[tid + TPB_E] = a1;
        } else if (scalar_next) {
            int avail = min(N - ntb, 1 << SSH);
            for (int i = tid; i < (1 << SSH); i += TPB_E)
                xt[cur ^ 1][i] = (i < avail) ? x[ntb + i] : 0.0f;
        }
        __syncthreads();   // next-buffer writes done; all reads of cur done
        cur ^= 1;
    }
    // dump partial accumulator (coalesced)
    float* po = partial + (((size_t)s * NC + c) << (DSH + 2));   // *16384
    for (int i = tid; i < (SUPER << DSH); i += TPB_E) po[i] = acc[i];
}

// combine NC partials per superbucket, divide by cnt
__global__ void combine_k(const float* __restrict__ partial, const float* __restrict__ cnt,
                          float* __restrict__ outslice, int N) {
    int tot4 = N >> 2;
    int stride = gridDim.x * blockDim.x;
    for (int n4 = blockIdx.x * blockDim.x + threadIdx.x; n4 < tot4; n4 += stride) {
        int n = n4 << 2;
        int s = n >> (DSH + 2);        // / 16384
        int i = n & ((SUPER << DSH) - 1);
        const float* pb = partial + (((size_t)s * NC) << (DSH + 2)) + i;
        float4 sum = *(const float4*)pb;
        #pragma unroll
        for (int cc = 1; cc < NC; ++cc) {
            float4 v = *(const float4*)(pb + ((size_t)cc << (DSH + 2)));
            sum.x += v.x; sum.y += v.y; sum.z += v.z; sum.w += v.w;
        }
        float4 cv = *(const float4*)(cnt + n);
        float4 o;
        o.x = sum.x / fmaxf(cv.x, 1.0f);
        o.y = sum.y / fmaxf(cv.y, 1.0f);
        o.z = sum.z / fmaxf(cv.z, 1.0f);
        o.w = sum.w / fmaxf(cv.w, 1.0f);
        *(float4*)(outslice + n) = o;
    }
    if (blockIdx.x == 0) {   // scalar tail (N not multiple of 4)
        for (int n = (tot4 << 2) + threadIdx.x; n < N; n += blockDim.x) {
            int s = n >> (DSH + 2);
            int i = n & ((SUPER << DSH) - 1);
            float sum = 0.0f;
            for (int cc = 0; cc < NC; ++cc)
                sum += partial[(((size_t)s * NC + cc) << (DSH + 2)) + i];
            outslice[n] = sum / fmaxf(cnt[n], 1.0f);
        }
    }
}

// ---------------- mid path: gather-style edge pass (round-5 proven) ----------------

__global__ __launch_bounds__(TPB_E)
void e_pass12(const float* __restrict__ x, const unsigned* __restrict__ packed,
              const unsigned* __restrict__ boff, const float* __restrict__ cnt,
              float* __restrict__ outslice, int N) {
    __shared__ float acc[1 << DSH];
    int tid = threadIdx.x;
    for (int i = tid; i < (1 << DSH); i += TPB_E) acc[i] = 0.0f;
    __syncthreads();
    int b = blockIdx.x;
    int beg = (int)boff[b], end = (int)boff[b + 1];
    int a0 = min((beg + 3) & ~3, end);
    for (int e = beg + tid; e < a0; e += TPB_E) {
        unsigned p = packed[e];
        atomicAdd(&acc[p & DMASK], x[p >> DSH]);
    }
    int i0 = a0 >> 2, i1 = i0 + ((end - a0) >> 2);
    const uint32x4* p4 = (const uint32x4*)packed;
    for (int i = i0 + tid; i < i1; i += TPB_E) {
        uint32x4 p = p4[i];
        atomicAdd(&acc[p.x & DMASK], x[p.x >> DSH]);
        atomicAdd(&acc[p.y & DMASK], x[p.y >> DSH]);
        atomicAdd(&acc[p.z & DMASK], x[p.z >> DSH]);
        atomicAdd(&acc[p.w & DMASK], x[p.w >> DSH]);
    }
    for (int e = a0 + ((end - a0) & ~3) + tid; e < end; e += TPB_E) {
        unsigned p = packed[e];
        atomicAdd(&acc[p & DMASK], x[p >> DSH]);
    }
    __syncthreads();
    int nbase = b << DSH;
    int nmax = min(N - nbase, 1 << DSH);
    for (int i = tid; i < nmax; i += TPB_E)
        outslice[nbase + i] = acc[i] / fmaxf(cnt[nbase + i], 1.0f);
}

// ---------------- fallback (global atomics) ----------------

#define TPB 256
#define MAX_BLOCKS 2048

__global__ void round_first(const float* __restrict__ x, const int* __restrict__ src,
                            const int* __restrict__ dst, float* __restrict__ agg,
                            float* __restrict__ cnt, int nE) {
    int i = blockIdx.x * blockDim.x + threadIdx.x;
    int stride = gridDim.x * blockDim.x;
    for (; i < nE; i += stride) {
        atomicAdd(&agg[dst[i]], x[src[i]]);
        atomicAdd(&cnt[dst[i]], 1.0f);
    }
}

__global__ void round_next(const float* __restrict__ x, const int* __restrict__ src,
                           const int* __restrict__ dst, float* __restrict__ agg, int nE) {
    int i = blockIdx.x * blockDim.x + threadIdx.x;
    int stride = gridDim.x * blockDim.x;
    for (; i < nE; i += stride) atomicAdd(&agg[dst[i]], x[src[i]]);
}

__global__ void normalize_k(float* __restrict__ out, const float* __restrict__ cnt, int n) {
    int i = blockIdx.x * blockDim.x + threadIdx.x;
    int stride = gridDim.x * blockDim.x;
    for (; i < n; i += stride) out[i] /= fmaxf(cnt[i], 1.0f);
}

// ---------------- launch ----------------

extern "C" void kernel_launch(void* const* d_in, const int* in_sizes, int n_in,
                              void* d_out, int out_size, void* d_ws, size_t ws_size,
                              hipStream_t stream) {
    const float* topic = (const float*)d_in[0];
    const int* ei  = (const int*)d_in[1];
    const int* rei = (const int*)d_in[2];
    const int N = in_sizes[0];
    const int E = in_sizes[1] / 2;

    float* out = (float*)d_out;   // 8 slices of N floats

    const int NDB = (N + (int)DMASK) >> DSH;
    const int NSB = (N + (int)SMASK) >> SSH;
    const int NSUP = (NDB + SUPER - 1) / SUPER;
    const int chunk = ((E + NPART * 16 - 1) / (NPART * 16)) * 16;

    size_t off = 0;
    auto alloc = [&](size_t bytes) { size_t o = off; off += (bytes + 255) & ~(size_t)255; return o; };
    size_t o_packed1 = alloc((size_t)E * 4);
    size_t o_cnt     = alloc((size_t)N * 4);
    size_t o_blkcnt  = alloc((size_t)NPART * NDB * 4);
    size_t o_start   = alloc((size_t)NPART * NDB * 4);
    size_t o_base    = alloc((size_t)(NDBMAX + 1) * 4);
    size_t need_mid  = off;
    size_t o_packed2 = alloc((size_t)E * 4);
    size_t o_celloff = alloc((size_t)NDB * (NSB + 1) * 4);
    size_t need_2d   = off;

    // partial accumulators reuse the packed1 region (dead after b_repart)
    size_t partial_elems = (size_t)NSUP * NC * (SUPER << DSH);

    bool shapes_ok = (NDB >= 2) && (NDB <= NDBMAX) && (NSB >= 1) && (NSB <= NSBMAX) &&
                     (N <= (1 << 20)) && (E % 16 == 0) && (E > 0);
    bool full = shapes_ok && (need_2d <= ws_size) && (partial_elems <= (size_t)E);
    bool mid  = shapes_ok && (need_mid <= ws_size);

    if (full || mid) {
        char* ws = (char*)d_ws;
        unsigned* packed1 = (unsigned*)(ws + o_packed1);
        float*    cnt     = (float*)   (ws + o_cnt);
        unsigned* blkcnt  = (unsigned*)(ws + o_blkcnt);
        unsigned* start   = (unsigned*)(ws + o_start);
        unsigned* base    = (unsigned*)(ws + o_base);
        unsigned* packed2 = full ? (unsigned*)(ws + o_packed2) : nullptr;
        unsigned* celloff = full ? (unsigned*)(ws + o_celloff) : nullptr;
        float*    partial = (float*)(ws + o_packed1);   // alias, safe ordering

        for (int dir = 0; dir < 2; ++dir) {
            const int* src = (dir == 0) ? ei : rei;
            const int* dst = src + E;
            float* oslab = out + (size_t)dir * 4 * N;

            // phase A ('start' head doubles as totals scratch; s3 overwrites it)
            p1_count<<<NPART, TPB_P, 0, stream>>>(dst, blkcnt, E, chunk, NDB);
            s1_totals<<<NDB, TPB_P, 0, stream>>>(blkcnt, start, NDB, NPART);
            s2_scan<<<1, TPB_P, 0, stream>>>(start, base, NDB);
            s3_start<<<NDB, TPB_P, 0, stream>>>(blkcnt, base, start, NDB, NPART);
            p2_scatter<<<NPART, TPB_P, 0, stream>>>(src, dst, start, packed1, E, chunk, NDB);

            c_pass<<<NDB, TPB_E, 0, stream>>>(packed1, base, cnt, N);

            if (full) {
                b_repart<<<NDB, TPB_E, 0, stream>>>(packed1, base, packed2, celloff, NSB);
                // packed1 is now dead -> its space holds 'partial'
                dim3 tg(NSUP, NC);
                const float* xin = topic;
                for (int r = 0; r < 4; ++r) {
                    t_pass2<<<tg, TPB_E, 0, stream>>>(xin, packed2, celloff, partial,
                                                      N, NDB, NSB);
                    combine_k<<<1024, 256, 0, stream>>>(partial, cnt,
                                                        oslab + (size_t)r * N, N);
                    xin = oslab + (size_t)r * N;
                }
            } else {
                e_pass12<<<NDB, TPB_E, 0, stream>>>(topic, packed1, base, cnt, oslab, N);
                for (int r = 1; r < 4; ++r)
                    e_pass12<<<NDB, TPB_E, 0, stream>>>(oslab + (size_t)(r - 1) * N, packed1,
                                                        base, cnt, oslab + (size_t)r * N, N);
            }
        }
        return;
    }

    // -------- fallback: global-atomic version --------
    const int* src = ei;
    const int* dst = ei + E;
    const int* rsrc = rei;
    const int* rdst = rei + E;

    float* cnt_f = (float*)d_ws;
    float* cnt_r = cnt_f + N;

    (void)hipMemsetAsync(d_out, 0, (size_t)out_size * sizeof(float), stream);
    (void)hipMemsetAsync(d_ws, 0, (size_t)2 * N * sizeof(float), stream);

    int eb = (E + TPB - 1) / TPB; if (eb > MAX_BLOCKS) eb = MAX_BLOCKS;
    int nb = (N + TPB - 1) / TPB; if (nb > MAX_BLOCKS) nb = MAX_BLOCKS;

    round_first<<<eb, TPB, 0, stream>>>(topic, src, dst, out, cnt_f, E);
    normalize_k<<<nb, TPB, 0, stream>>>(out, cnt_f, N);
    for (int r = 1; r < 4; ++r) {
        round_next<<<eb, TPB, 0, stream>>>(out + (size_t)(r - 1) * N, src, dst,
                                           out + (size_t)r * N, E);
        normalize_k<<<nb, TPB, 0, stream>>>(out + (size_t)r * N, cnt_f, N);
    }
    round_first<<<eb, TPB, 0, stream>>>(topic, rsrc, rdst, out + (size_t)4 * N, cnt_r, E);
    normalize_k<<<nb, TPB, 0, stream>>>(out + (size_t)4 * N, cnt_r, N);
    for (int r = 5; r < 8; ++r) {
        round_next<<<eb, TPB, 0, stream>>>(out + (size_t)(r - 1) * N, rsrc, rdst,
                                           out + (size_t)r * N, E);
        normalize_k<<<nb, TPB, 0, stream>>>(out + (size_t)r * N, cnt_r, N);
    }
}